// Round 7
// baseline (289.807 us; speedup 1.0000x reference)
//
#include <hip/hip_runtime.h>

#define B_ 2
#define S_ 2048
#define D_ 2048
#define H_ 16
#define HD_ 128
#define NT_ (S_ / 64)
#define NBUF 6

typedef unsigned short u16;
typedef __bf16 bf16x8 __attribute__((ext_vector_type(8)));
typedef float f32x4 __attribute__((ext_vector_type(4)));
typedef u16 u16x8 __attribute__((ext_vector_type(8)));

__device__ __forceinline__ float bf2f(u16 u) {
  unsigned int x = ((unsigned int)u) << 16;
  return __builtin_bit_cast(float, x);
}
__device__ __forceinline__ u16 f2bf(float f) {
  unsigned int u = __builtin_bit_cast(unsigned int, f);
  u += 0x7fffu + ((u >> 16) & 1u);
  return (u16)(u >> 16);
}
__device__ __forceinline__ void async16(const void* g, void* l) {
  __builtin_amdgcn_global_load_lds((const __attribute__((address_space(1))) void*)g,
                                   (__attribute__((address_space(3))) void*)l, 16, 0, 0);
}
__device__ __forceinline__ float vexp2(float x) {
  float r;
  asm("v_exp_f32 %0, %1" : "=v"(r) : "v"(x));
  return r;
}
__device__ __forceinline__ float vrcp(float x) {
  float r;
  asm("v_rcp_f32 %0, %1" : "=v"(r) : "v"(x));
  return r;
}

// ---------------- elementwise fp32 -> bf16 ----------------
__global__ __launch_bounds__(256) void conv_f32_bf16(const float* __restrict__ in,
                                                     u16* __restrict__ outp, int n) {
  int idx = (blockIdx.x * 256 + threadIdx.x) * 4;
  int stride = gridDim.x * 256 * 4;
  for (; idx < n; idx += stride) {
    float4 v = *(const float4*)(in + idx);
    ushort4 ov = make_ushort4(f2bf(v.x), f2bf(v.y), f2bf(v.z), f2bf(v.w));
    *(ushort4*)(outp + idx) = ov;
  }
}

// ---------------- w_in transpose+convert with sigma column permutation ----------------
__global__ __launch_bounds__(256) void transpose_win(const float* __restrict__ in,
                                                     u16* __restrict__ outp) {
  __shared__ float tile[32][33];
  int n0 = blockIdx.x * 32, k0 = blockIdx.y * 32;
  int tx = threadIdx.x & 31, ty = threadIdx.x >> 5;
  int n = n0 + tx;
  int cc = n >> 7, p = n & 127;
  int q = (p >> 4) & 3;
  int d = ((p >> 6) << 5) + ((q >> 1) << 4) + ((q & 1) << 6) + (p & 15);
  int f = (cc / 3) * 384 + (cc % 3) * 128 + d;
#pragma unroll
  for (int yy = 0; yy < 32; yy += 8)
    tile[ty + yy][tx] = in[(size_t)(k0 + ty + yy) * 6144 + f];
  __syncthreads();
#pragma unroll
  for (int yy = 0; yy < 32; yy += 8)
    outp[(size_t)(n0 + ty + yy) * 2048 + k0 + tx] = f2bf(tile[tx][ty + yy]);
}

// ---------------- w_out transpose+convert with row permutation matching X' layout ----------
// out[n][k'] = w_out[perm(k')][n], perm(k') = h*128 + hd, h=k'>>7, j=k'&127, hd=(j&7)*16+(j>>3)
__global__ __launch_bounds__(256) void transpose_wout(const float* __restrict__ in,
                                                      u16* __restrict__ outp) {
  __shared__ float tile[32][33];
  int k0 = blockIdx.x * 32, n0 = blockIdx.y * 32;
  int tx = threadIdx.x & 31, ty = threadIdx.x >> 5;
#pragma unroll
  for (int yy = 0; yy < 32; yy += 8) {
    int kk = k0 + ty + yy;
    int hh = kk >> 7, j = kk & 127;
    int hd = (j & 7) * 16 + (j >> 3);
    tile[ty + yy][tx] = in[(size_t)(hh * 128 + hd) * 2048 + n0 + tx];
  }
  __syncthreads();
#pragma unroll
  for (int yy = 0; yy < 32; yy += 8)
    outp[(size_t)(n0 + ty + yy) * 2048 + k0 + tx] = f2bf(tile[tx][ty + yy]);
}

// ================= m201-schedule 256x256 GEMM, BK=64, 8 phases =================
// EPI==1 epilogue: in-register RoPE on Q/K stored in FRAGMENT-NATIVE permuted order
// (j = wn1*64 + lr*4 + t*2 + half; both Q and K identically permuted -> QK^T invariant),
// packed ushort4 stores; V written transposed (B,H,HD,S). EPI==0: plain fp32 C.
#define BAR __builtin_amdgcn_s_barrier()
#define LGKM0                                          \
  {                                                    \
    asm volatile("s_waitcnt lgkmcnt(0)" ::: "memory"); \
    __builtin_amdgcn_sched_barrier(0);                 \
  }
#define VM4 asm volatile("s_waitcnt vmcnt(4)" ::: "memory")
#define VM0 asm volatile("s_waitcnt vmcnt(0)" ::: "memory")
#define P1 __builtin_amdgcn_s_setprio(1)
#define P0 __builtin_amdgcn_s_setprio(0)

template <int EPI>
__global__ __launch_bounds__(512, 1) void gemm256_8p(
    const u16* __restrict__ A, const u16* __restrict__ Bt, float* __restrict__ C, int K, int N,
    int ntn, u16* __restrict__ Qo, u16* __restrict__ Ko, u16* __restrict__ Vo,
    const float* __restrict__ rsin, const float* __restrict__ rcos) {
  __shared__ alignas(16) u16 lsA[2][256 * 64];
  __shared__ alignas(16) u16 lsB[2][256 * 64];
  const int tid = threadIdx.x;
  const int lane = tid & 63, wid = tid >> 6;
  const int g = lane >> 4, lr = lane & 15;
  const int wm = wid >> 2, wn = wid & 3;  // 2M x 4N

  const int nwg = 16 * ntn;
  const int bid = blockIdx.x;
  const int swz = (bid & 7) * (nwg >> 3) + (bid >> 3);
  const int m_idx = swz & 15, n_idx = swz >> 4;
  const size_t m0 = (size_t)m_idx * 256, n0 = (size_t)n_idx * 256;

  const int row0 = tid >> 3, sl0 = tid & 7;
  const int row1 = (512 + tid) >> 3, sl1 = tid & 7;
  const u16* pA0 = A + (m0 + row0) * K + ((sl0 ^ (row0 & 7)) << 3);
  const u16* pA1 = A + (m0 + row1) * K + ((sl1 ^ (row1 & 7)) << 3);
  const u16* pB0 = Bt + (n0 + row0) * K + ((sl0 ^ (row0 & 7)) << 3);
  const u16* pB1 = Bt + (n0 + row1) * K + ((sl1 ^ (row1 & 7)) << 3);
  const size_t hstep = (size_t)128 * K;

#define STG_A(t, buf, half)                                                                        \
  {                                                                                                \
    async16(pA0 + (half)*hstep + (size_t)(t)*64, (char*)lsA[buf] + (half)*16384 + tid * 16);       \
    async16(pA1 + (half)*hstep + (size_t)(t)*64, (char*)lsA[buf] + (half)*16384 + 8192 + tid * 16); \
  }
#define STG_B(t, buf, half)                                                                        \
  {                                                                                                \
    async16(pB0 + (half)*hstep + (size_t)(t)*64, (char*)lsB[buf] + (half)*16384 + tid * 16);       \
    async16(pB1 + (half)*hstep + (size_t)(t)*64, (char*)lsB[buf] + (half)*16384 + 8192 + tid * 16); \
  }

  const int sw0 = ((g) ^ (lr & 7)) << 4;
  const int sw1 = ((4 + g) ^ (lr & 7)) << 4;

#define LDA(tb, mh)                                                                      \
  {                                                                                      \
    _Pragma("unroll") for (int i2 = 0; i2 < 4; ++i2) {                                   \
      const char* _p = (const char*)lsA[tb] + (wm * 128 + (mh)*64 + i2 * 16 + lr) * 128; \
      aF[i2][0] = *(const bf16x8*)(_p + sw0);                                            \
      aF[i2][1] = *(const bf16x8*)(_p + sw1);                                            \
    }                                                                                    \
  }
#define LDB(tb, dst, nh)                                                                \
  {                                                                                     \
    _Pragma("unroll") for (int j2 = 0; j2 < 2; ++j2) {                                  \
      const char* _p = (const char*)lsB[tb] + (wn * 64 + (nh)*32 + j2 * 16 + lr) * 128; \
      dst[j2][0] = *(const bf16x8*)(_p + sw0);                                          \
      dst[j2][1] = *(const bf16x8*)(_p + sw1);                                          \
    }                                                                                   \
  }
#define MM(mh, nh, BB)                                                                       \
  {                                                                                          \
    _Pragma("unroll") for (int i2 = 0; i2 < 4; ++i2) _Pragma("unroll") for (int j2 = 0;     \
                                                                            j2 < 2; ++j2) { \
      acc[(mh)*4 + i2][(nh)*2 + j2] = __builtin_amdgcn_mfma_f32_16x16x32_bf16(               \
          aF[i2][0], BB[j2][0], acc[(mh)*4 + i2][(nh)*2 + j2], 0, 0, 0);                     \
      acc[(mh)*4 + i2][(nh)*2 + j2] = __builtin_amdgcn_mfma_f32_16x16x32_bf16(               \
          aF[i2][1], BB[j2][1], acc[(mh)*4 + i2][(nh)*2 + j2], 0, 0, 0);                     \
    }                                                                                        \
  }

  f32x4 acc[8][4] = {};
  const int nk2 = K >> 7;

  STG_A(0, 0, 0);
  STG_B(0, 0, 1);
  STG_B(0, 0, 0);
  STG_A(0, 0, 1);
  STG_A(1, 1, 0);
  STG_B(1, 1, 1);
  VM4;
  BAR;

  bf16x8 aF[4][2], b0[2][2], b1[2][2];
#pragma unroll 1
  for (int it = 0; it < nk2 - 1; ++it) {
    const int t1 = 2 * it + 1, s2 = 2 * it + 2, s3 = 2 * it + 3;
    LDA(0, 0);
    LDB(0, b0, 0);
    STG_B(t1, 1, 0);
    BAR; LGKM0; P1; MM(0, 0, b0); P0; BAR;
    LDB(0, b1, 1);
    STG_A(t1, 1, 1);
    BAR; LGKM0; P1; MM(0, 1, b1); P0; BAR;
    LDA(0, 1);
    STG_A(s2, 0, 0);
    BAR; LGKM0; P1; MM(1, 1, b1); P0; BAR;
    STG_B(s2, 0, 1);
    BAR; LGKM0; P1; MM(1, 0, b0); P0;
    VM4;
    BAR;
    LDA(1, 0);
    LDB(1, b0, 0);
    STG_B(s2, 0, 0);
    BAR; LGKM0; P1; MM(0, 0, b0); P0; BAR;
    LDB(1, b1, 1);
    STG_A(s2, 0, 1);
    BAR; LGKM0; P1; MM(0, 1, b1); P0; BAR;
    LDA(1, 1);
    STG_A(s3, 1, 0);
    BAR; LGKM0; P1; MM(1, 1, b1); P0; BAR;
    STG_B(s3, 1, 1);
    BAR; LGKM0; P1; MM(1, 0, b0); P0;
    VM4;
    BAR;
  }
  {
    const int t1 = 2 * (nk2 - 1) + 1;
    LDA(0, 0);
    LDB(0, b0, 0);
    STG_B(t1, 1, 0);
    BAR; LGKM0; P1; MM(0, 0, b0); P0; BAR;
    LDB(0, b1, 1);
    STG_A(t1, 1, 1);
    BAR; LGKM0; P1; MM(0, 1, b1); P0; BAR;
    LDA(0, 1);
    BAR; LGKM0; P1; MM(1, 1, b1); P0; BAR;
    BAR; LGKM0; P1; MM(1, 0, b0); P0;
    VM0;
    BAR;
    LDA(1, 0);
    LDB(1, b0, 0);
    BAR; LGKM0; P1; MM(0, 0, b0); P0; BAR;
    LDB(1, b1, 1);
    BAR; LGKM0; P1; MM(0, 1, b1); P0; BAR;
    LDA(1, 1);
    BAR; LGKM0; P1; MM(1, 1, b1); P0; BAR;
    BAR; LGKM0; P1; MM(1, 0, b0); P0; BAR;
  }
#undef STG_A
#undef STG_B
#undef LDA
#undef LDB
#undef MM

  if (EPI == 0) {
#pragma unroll
    for (int ai = 0; ai < 8; ++ai)
#pragma unroll
      for (int bj = 0; bj < 4; ++bj)
#pragma unroll
        for (int r = 0; r < 4; ++r) {
          size_t m = m0 + wm * 128 + (ai >> 2) * 64 + (ai & 3) * 16 + 4 * g + r;
          size_t n = n0 + wn * 64 + (bj >> 1) * 32 + (bj & 1) * 16 + lr;
          C[m * N + n] = acc[ai][bj][r];
        }
  } else {
    const int c = (int)(n0 >> 7) + (wn >> 1);
    const int h = c / 3, part = c % 3;
    const int wn1 = wn & 1;
    if (part == 2) {
      // V: un-permute sigma, write transposed (B,H,HD,S)
#pragma unroll
      for (int ai = 0; ai < 8; ++ai) {
        int m = (int)m0 + wm * 128 + (ai >> 2) * 64 + (ai & 3) * 16 + 4 * g;
        int b = m >> 11, s = m & (S_ - 1);
#pragma unroll
        for (int bj = 0; bj < 4; ++bj) {
          int hd = wn1 * 32 + ((bj >> 1) << 4) + ((bj & 1) << 6) + lr;
          ushort4 pk;
          pk.x = f2bf(acc[ai][bj][0]);
          pk.y = f2bf(acc[ai][bj][1]);
          pk.z = f2bf(acc[ai][bj][2]);
          pk.w = f2bf(acc[ai][bj][3]);
          *(ushort4*)(Vo + ((size_t)(b * H_ + h) * HD_ + hd) * S_ + s) = pk;
        }
      }
    } else {
      // Q/K: in-register RoPE, stored in fragment-native order:
      // Q'[s][j], j = wn1*64 + lr*4 + t*2 + half; value = rope(d), d = wn1*32+t*16+lr (+64*half)
      u16* dstp = (part == 0) ? Qo : Ko;
      const float scl = (part == 0) ? 0.08838834764831845f : 1.0f;
#pragma unroll
      for (int ai = 0; ai < 8; ++ai) {
        int mbase = (int)m0 + wm * 128 + (ai >> 2) * 64 + (ai & 3) * 16 + 4 * g;
#pragma unroll
        for (int r = 0; r < 4; ++r) {
          int m = mbase + r;
          int b = m >> 11, s = m & (S_ - 1);
          const float* srow = rsin + s * 64;
          const float* crow = rcos + s * 64;
          u16* op = dstp + ((size_t)(b * H_ + h) * S_ + s) * HD_ + ((wn1 * 16 + lr) << 2);
          ushort4 pk;
#pragma unroll
          for (int t = 0; t < 2; ++t) {
            int d = wn1 * 32 + t * 16 + lr;
            float cv = crow[d] * scl, sv = srow[d] * scl;
            float x1 = acc[ai][t * 2][r], x2 = acc[ai][t * 2 + 1][r];
            if (t == 0) {
              pk.x = f2bf(x1 * cv - x2 * sv);
              pk.y = f2bf(x2 * cv + x1 * sv);
            } else {
              pk.z = f2bf(x1 * cv - x2 * sv);
              pk.w = f2bf(x2 * cv + x1 * sv);
            }
          }
          *(ushort4*)op = pk;
        }
      }
    }
  }
}

// ---------------- R3 deep-pipelined 256x128 GEMM (gemm2) ----------------
template <int EPI>
__global__ __launch_bounds__(512, 1) void gemm8p(const u16* __restrict__ A,
                                                 const u16* __restrict__ Bt,
                                                 float* __restrict__ C, int K, int N, int gx,
                                                 u16* __restrict__ Qo, u16* __restrict__ Ko,
                                                 u16* __restrict__ Vo) {
  __shared__ alignas(16) u16 lsA[NBUF][256 * 32];
  __shared__ alignas(16) u16 lsB[NBUF][128 * 32];
  const int tid = threadIdx.x;
  const int lane = tid & 63;
  const int wid = tid >> 6;
  const int g = lane >> 4, lr = lane & 15;
  const int wm = wid >> 1, wn = wid & 1;

  const int nwg = gx << 4;
  const int bid = blockIdx.x;
  const int swz = (bid & 7) * (nwg >> 3) + (bid >> 3);
  const int m_idx = swz & 15, n_idx = swz >> 4;
  const size_t m0 = (size_t)m_idx * 256, n0 = (size_t)n_idx * 128;

  const int la0 = tid, la1 = 512 + tid;
  const int rowA0 = la0 >> 2, slA0 = la0 & 3;
  const int rowA1 = la1 >> 2, slA1 = la1 & 3;
  const int rowB = tid >> 2, slB = tid & 3;
  const u16* srcA0 = A + (m0 + rowA0) * K + ((slA0 ^ ((rowA0 >> 1) & 3)) << 3);
  const u16* srcA1 = A + (m0 + rowA1) * K + ((slA1 ^ ((rowA1 >> 1) & 3)) << 3);
  const u16* srcB = Bt + (n0 + rowB) * K + ((slB ^ ((rowB >> 1) & 3)) << 3);

#define STAGE(t, bufi)                                  \
  {                                                     \
    const int koff = (t) << 5;                          \
    async16(srcA0 + koff, (char*)lsA[bufi] + la0 * 16); \
    async16(srcA1 + koff, (char*)lsA[bufi] + la1 * 16); \
    async16(srcB + koff, (char*)lsB[bufi] + tid * 16);  \
  }

  int ofsA[4], ofsB[4];
#pragma unroll
  for (int i = 0; i < 4; ++i) {
    int ra = wm * 64 + i * 16 + lr;
    ofsA[i] = ra * 64 + ((g ^ ((ra >> 1) & 3)) << 4);
    int rb = wn * 64 + i * 16 + lr;
    ofsB[i] = rb * 64 + ((g ^ ((rb >> 1) & 3)) << 4);
  }

  f32x4 acc[4][4] = {};
  const int nk = K >> 5;

#pragma unroll
  for (int t = 0; t < NBUF - 1; ++t) STAGE(t, t);
  asm volatile("s_waitcnt vmcnt(12)" ::: "memory");
  __builtin_amdgcn_s_barrier();

  int buf = 0;
#pragma unroll 1
  for (int kt = 0; kt < nk; ++kt) {
    bf16x8 af[4], bfr[4];
#pragma unroll
    for (int i = 0; i < 4; ++i) af[i] = *(const bf16x8*)((const char*)lsA[buf] + ofsA[i]);
#pragma unroll
    for (int j = 0; j < 4; ++j) bfr[j] = *(const bf16x8*)((const char*)lsB[buf] + ofsB[j]);
    const int st = kt + NBUF - 1;
    const int sbuf = buf == 0 ? NBUF - 1 : buf - 1;
    if (st < nk) STAGE(st, sbuf);
    __builtin_amdgcn_s_barrier();
    __builtin_amdgcn_s_setprio(1);
#pragma unroll
    for (int i = 0; i < 4; ++i)
#pragma unroll
      for (int j = 0; j < 4; ++j)
        acc[i][j] = __builtin_amdgcn_mfma_f32_16x16x32_bf16(af[i], bfr[j], acc[i][j], 0, 0, 0);
    __builtin_amdgcn_s_setprio(0);
    asm volatile("s_waitcnt vmcnt(12)" ::: "memory");
    __builtin_amdgcn_s_barrier();
    buf = buf == NBUF - 1 ? 0 : buf + 1;
  }
#undef STAGE

  if (EPI == 0) {
#pragma unroll
    for (int i = 0; i < 4; ++i)
#pragma unroll
      for (int j = 0; j < 4; ++j)
#pragma unroll
        for (int r = 0; r < 4; ++r) {
          size_t m = m0 + wm * 64 + i * 16 + 4 * g + r;
          size_t n = n0 + wn * 64 + j * 16 + lr;
          C[m * N + n] = acc[i][j][r];
        }
  }
}

// ---------------- flash attention: paired q-tiles, 8 waves, shared K/V staging ----------------
// Q,K (B,H,S,HD) in sigma-permuted j-layout (both identical -> QK^T invariant), Q pre-scaled.
// VT (B,H,HD,S). X out: (B,S,H,HD) in attn-native j2-layout (w_outT rows permuted to match).
// grid = (8, 32), block 512 = 8 waves. Waves 0-3 -> tile qa=2u, waves 4-7 -> tile qb=2u+1.
// Two passes (u = 15-bx, then u = bx) -> uniform 34 tile-iters per block. K/V staged once
// per kt for both tiles (traffic halved vs 64-row blocks).
__global__ __launch_bounds__(512, 1) void attn_fwd(const u16* __restrict__ Q, const u16* __restrict__ K,
                                                   const u16* __restrict__ VT, u16* __restrict__ X) {
  const int bx = blockIdx.x;
  const int bh = blockIdx.y;
  const int tid = threadIdx.x;
  const int lane = tid & 63, wid = tid >> 6;
  const int g = lane >> 4, lr = lane & 15;
  const int wq = wid & 3;   // row-group within tile
  const int tb = wid >> 2;  // 0 = tile a, 1 = tile b

  __shared__ alignas(16) u16 lsK[2][64 * 128];
  __shared__ alignas(16) u16 lsV[2][128 * 64];
  __shared__ alignas(16) u16 lsP[8][16 * 72];

  const u16* Qp = Q + (size_t)bh * S_ * HD_;
  const u16* Kp = K + (size_t)bh * S_ * HD_;
  const u16* Vp = VT + (size_t)bh * HD_ * S_;
  u16* myP = lsP[wid];
  const int b = bh >> 4, h = bh & 15;

  const float c1 = -0.057707802f;   // -0.04 * log2(e)
  const float c2 = -144.26950409f;  // -100 * log2(e)

#pragma unroll 1
  for (int pass = 0; pass < 2; ++pass) {
    const int u = pass ? bx : (15 - bx);
    const int qa = 2 * u, qb = qa + 1;
    const int qt = qa + tb;  // this wave's q-tile
    const int qrow = qt * 64 + wq * 16 + lr;
    const int qbase = qt * 64 + wq * 16 + 4 * g;

    bf16x8 qf[4];
#pragma unroll
    for (int kc = 0; kc < 4; ++kc)
      qf[kc] = *(const bf16x8*)(Qp + (size_t)qrow * HD_ + kc * 32 + g * 8);

    f32x4 o[8] = {};
    float psum[4] = {0.f, 0.f, 0.f, 0.f};

    // prologue: stage tile 0 into buffer 0 (512 threads: 2 chunks each for K and V)
#pragma unroll
    for (int p = 0; p < 2; ++p) {
      int c = p * 512 + tid;
      int rowk = c >> 4;
      int wsk = ((c & 15) << 4) ^ ((rowk & 7) << 4);
      async16((const char*)Kp + (((size_t)rowk) << 8) + wsk, (char*)lsK[0] + c * 16);
      int rowv = c >> 3;
      int wsv = ((c & 7) << 4) ^ ((rowv & 7) << 4);
      async16((const char*)Vp + (size_t)rowv * (S_ * 2) + wsv, (char*)lsV[0] + c * 16);
    }
    __syncthreads();

    int cur = 0;
    for (int kt = 0; kt <= qb; ++kt) {
      if (kt < qb) {
        const int nxt = kt + 1;
#pragma unroll
        for (int p = 0; p < 2; ++p) {
          int c = p * 512 + tid;
          int rowk = c >> 4;
          int wsk = ((c & 15) << 4) ^ ((rowk & 7) << 4);
          async16((const char*)Kp + (((size_t)(nxt * 64 + rowk)) << 8) + wsk,
                  (char*)lsK[cur ^ 1] + c * 16);
          int rowv = c >> 3;
          int wsv = ((c & 7) << 4) ^ ((rowv & 7) << 4);
          async16((const char*)Vp + (size_t)rowv * (S_ * 2) + nxt * 128 + wsv,
                  (char*)lsV[cur ^ 1] + c * 16);
        }
      }
      if (tb | (kt <= qa)) {  // tile-a waves skip kt == qb
        f32x4 sc[4];
#pragma unroll
        for (int jn = 0; jn < 4; ++jn) {
          f32x4 a = {0.f, 0.f, 0.f, 0.f};
          const int row = jn * 16 + lr;
          const int sw = (row & 7) << 4;
#pragma unroll
          for (int kc = 0; kc < 4; ++kc) {
            int w = (kc * 64 + g * 16) ^ sw;
            bf16x8 kf = *(const bf16x8*)((const char*)lsK[cur] + row * 256 + w);
            a = __builtin_amdgcn_mfma_f32_16x16x32_bf16(qf[kc], kf, a, 0, 0, 0);
          }
          sc[jn] = a;
        }
#pragma unroll
        for (int jn = 0; jn < 4; ++jn) {
          int key = kt * 64 + jn * 16 + lr;
#pragma unroll
          for (int r = 0; r < 4; ++r) {
            float z = vexp2(c1 * sc[jn][r]);
            float p = vexp2(c2 * z * vrcp(1.f + z));
            if (key > qbase + r) p = 0.f;
            psum[r] += p;
            myP[(4 * g + r) * 72 + jn * 16 + lr] = f2bf(p);
          }
        }
#pragma unroll
        for (int kc = 0; kc < 2; ++kc) {
          bf16x8 pa = *(const bf16x8*)(myP + lr * 72 + kc * 32 + g * 8);
#pragma unroll
          for (int jh = 0; jh < 8; ++jh) {
            int row = jh * 16 + lr;
            int w = (kc * 64 + g * 16) ^ ((row & 7) << 4);
            bf16x8 vf = *(const bf16x8*)((const char*)lsV[cur] + row * 128 + w);
            o[jh] = __builtin_amdgcn_mfma_f32_16x16x32_bf16(pa, vf, o[jh], 0, 0, 0);
          }
        }
      }
      __syncthreads();
      cur ^= 1;
    }
    // epilogue: reduce row-sums, normalize, write X in native j2-layout (one 16B store per row)
    float lsum[4];
#pragma unroll
    for (int r = 0; r < 4; ++r) {
      float s = psum[r];
#pragma unroll
      for (int msk = 1; msk < 16; msk <<= 1) s += __shfl_xor(s, msk, 64);
      lsum[r] = s;
    }
#pragma unroll
    for (int r = 0; r < 4; ++r) {
      float inv = 1.f / lsum[r];
      int s = qbase + r;
      u16x8 pk;
#pragma unroll
      for (int jh = 0; jh < 8; ++jh) pk[jh] = f2bf(o[jh][r] * inv);
      *(u16x8*)(X + ((size_t)(b * S_ + s)) * D_ + h * HD_ + lr * 8) = pk;
    }
  }
}

extern "C" void kernel_launch(void* const* d_in, const int* in_sizes, int n_in,
                              void* d_out, int out_size, void* d_ws, size_t ws_size,
                              hipStream_t stream) {
  const float* inputs = (const float*)d_in[0];
  const float* w_in = (const float*)d_in[1];
  const float* w_out = (const float*)d_in[2];
  const float* rsin = (const float*)d_in[3];
  const float* rcos = (const float*)d_in[4];
  float* out = (float*)d_out;

  char* ws = (char*)d_ws;
  u16* bfA = (u16*)(ws);                // (B*S, D) bf16
  u16* w_inT = (u16*)(ws + 16777216);   // (6144, 2048) bf16, sigma-permuted cols
  u16* Qraw = (u16*)(ws + 41943040);    // (B,H,S,HD) roped, j-layout, Q pre-scaled
  u16* Kraw = (u16*)(ws + 58720256);    // (B,H,S,HD) roped, j-layout
  u16* VT = (u16*)(ws + 75497472);      // (B,H,HD,S)
  u16* Xbuf = (u16*)(ws);               // reuse bfA region, j2-layout
  u16* w_outT = (u16*)(ws + 16777216);  // reuse w_inT region, row-permuted

  conv_f32_bf16<<<2048, 256, 0, stream>>>(inputs, bfA, B_ * S_ * D_);
  transpose_win<<<dim3(192, 64), 256, 0, stream>>>(w_in, w_inT);
  gemm256_8p<1><<<384, 512, 0, stream>>>(bfA, w_inT, nullptr, 2048, 6144, 24, Qraw, Kraw, VT,
                                         rsin, rcos);
  transpose_wout<<<dim3(64, 64), 256, 0, stream>>>(w_out, w_outT);
  attn_fwd<<<dim3(8, 32), 512, 0, stream>>>(Qraw, Kraw, VT, Xbuf);
  gemm8p<0><<<256, 512, 0, stream>>>(Xbuf, w_outT, out, 2048, 2048, 16,
                                     nullptr, nullptr, nullptr);
}

// Round 8
// 278.326 us; speedup vs baseline: 1.0413x; 1.0413x over previous
//
#include <hip/hip_runtime.h>

#define B_ 2
#define S_ 2048
#define D_ 2048
#define H_ 16
#define HD_ 128
#define NT_ (S_ / 64)

typedef unsigned short u16;
typedef __bf16 bf16x8 __attribute__((ext_vector_type(8)));
typedef float f32x4 __attribute__((ext_vector_type(4)));
typedef u16 u16x8 __attribute__((ext_vector_type(8)));

__device__ __forceinline__ float bf2f(u16 u) {
  unsigned int x = ((unsigned int)u) << 16;
  return __builtin_bit_cast(float, x);
}
__device__ __forceinline__ u16 f2bf(float f) {
  unsigned int u = __builtin_bit_cast(unsigned int, f);
  u += 0x7fffu + ((u >> 16) & 1u);
  return (u16)(u >> 16);
}
__device__ __forceinline__ void async16(const void* g, void* l) {
  __builtin_amdgcn_global_load_lds((const __attribute__((address_space(1))) void*)g,
                                   (__attribute__((address_space(3))) void*)l, 16, 0, 0);
}
__device__ __forceinline__ float vexp2(float x) {
  float r;
  asm("v_exp_f32 %0, %1" : "=v"(r) : "v"(x));
  return r;
}
__device__ __forceinline__ float vrcp(float x) {
  float r;
  asm("v_rcp_f32 %0, %1" : "=v"(r) : "v"(x));
  return r;
}

// ---------------- elementwise fp32 -> bf16 ----------------
__global__ __launch_bounds__(256) void conv_f32_bf16(const float* __restrict__ in,
                                                     u16* __restrict__ outp, int n) {
  int idx = (blockIdx.x * 256 + threadIdx.x) * 4;
  int stride = gridDim.x * 256 * 4;
  for (; idx < n; idx += stride) {
    float4 v = *(const float4*)(in + idx);
    ushort4 ov = make_ushort4(f2bf(v.x), f2bf(v.y), f2bf(v.z), f2bf(v.w));
    *(ushort4*)(outp + idx) = ov;
  }
}

// ---------------- w_in transpose+convert with sigma column permutation ----------------
__global__ __launch_bounds__(256) void transpose_win(const float* __restrict__ in,
                                                     u16* __restrict__ outp) {
  __shared__ float tile[32][33];
  int n0 = blockIdx.x * 32, k0 = blockIdx.y * 32;
  int tx = threadIdx.x & 31, ty = threadIdx.x >> 5;
  int n = n0 + tx;
  int cc = n >> 7, p = n & 127;
  int q = (p >> 4) & 3;
  int d = ((p >> 6) << 5) + ((q >> 1) << 4) + ((q & 1) << 6) + (p & 15);
  int f = (cc / 3) * 384 + (cc % 3) * 128 + d;
#pragma unroll
  for (int yy = 0; yy < 32; yy += 8)
    tile[ty + yy][tx] = in[(size_t)(k0 + ty + yy) * 6144 + f];
  __syncthreads();
#pragma unroll
  for (int yy = 0; yy < 32; yy += 8)
    outp[(size_t)(n0 + ty + yy) * 2048 + k0 + tx] = f2bf(tile[tx][ty + yy]);
}

// ---------------- w_out transpose+convert with row permutation matching X' layout ----------
__global__ __launch_bounds__(256) void transpose_wout(const float* __restrict__ in,
                                                      u16* __restrict__ outp) {
  __shared__ float tile[32][33];
  int k0 = blockIdx.x * 32, n0 = blockIdx.y * 32;
  int tx = threadIdx.x & 31, ty = threadIdx.x >> 5;
#pragma unroll
  for (int yy = 0; yy < 32; yy += 8) {
    int kk = k0 + ty + yy;
    int hh = kk >> 7, j = kk & 127;
    int hd = (j & 7) * 16 + (j >> 3);
    tile[ty + yy][tx] = in[(size_t)(hh * 128 + hd) * 2048 + n0 + tx];
  }
  __syncthreads();
#pragma unroll
  for (int yy = 0; yy < 32; yy += 8)
    outp[(size_t)(n0 + ty + yy) * 2048 + k0 + tx] = f2bf(tile[tx][ty + yy]);
}

// ================= 128x256 GEMM, BK=64, 3-deep ring, 2 phases/K-tile =================
// Grids: QKV 32x24=768 (3 full rounds), out-proj 32x8=256 (1 full round).
// 8 waves (2M x 4N), per-wave 64x64, 16 MFMA/phase. Counted vmcnt(6): one K-tile's
// 6 loads in flight across tile boundary; ring buf (kt+2)%3 last read at kt-1.
#define BAR __builtin_amdgcn_s_barrier()
#define LGKM0                                          \
  {                                                    \
    asm volatile("s_waitcnt lgkmcnt(0)" ::: "memory"); \
    __builtin_amdgcn_sched_barrier(0);                 \
  }
#define VM6 asm volatile("s_waitcnt vmcnt(6)" ::: "memory")
#define VM0 asm volatile("s_waitcnt vmcnt(0)" ::: "memory")
#define P1 __builtin_amdgcn_s_setprio(1)
#define P0 __builtin_amdgcn_s_setprio(0)

template <int EPI>
__global__ __launch_bounds__(512, 1) void gemm128(
    const u16* __restrict__ A, const u16* __restrict__ Bt, float* __restrict__ C, int K, int N,
    int ntn, u16* __restrict__ Qo, u16* __restrict__ Ko, u16* __restrict__ Vo,
    const float* __restrict__ rsin, const float* __restrict__ rcos) {
  __shared__ alignas(16) u16 lsA[3][128 * 64];
  __shared__ alignas(16) u16 lsB[3][256 * 64];
  const int tid = threadIdx.x;
  const int lane = tid & 63, wid = tid >> 6;
  const int g = lane >> 4, lr = lane & 15;
  const int wm = wid >> 2, wn = wid & 3;  // 2M x 4N, wave tile 64x64

  // bijective XCD swizzle (nwg % 8 == 0 at both call sites)
  const int nwg = ntn << 5;  // 32 m-tiles always
  const int bid = blockIdx.x;
  const int swz = (bid & 7) * (nwg >> 3) + (bid >> 3);
  const int m_idx = swz & 31, n_idx = swz >> 5;
  const size_t m0 = (size_t)m_idx * 128, n0 = (size_t)n_idx * 256;

  // staging sources: chunk idx -> row = idx>>3, slot = idx&7; global k pre-swizzled
  const int rowq = tid >> 3, slq = tid & 7;
  const int kofs = (slq ^ (rowq & 7)) << 3;
  const u16* pA0 = A + (m0 + rowq) * K + kofs;       // rows 0..63
  const u16* pA1 = A + (m0 + 64 + rowq) * K + kofs;  // rows 64..127
  const u16* pB0 = Bt + (n0 + rowq) * K + kofs;
  const u16* pB1 = Bt + (n0 + 64 + rowq) * K + kofs;
  const u16* pB2 = Bt + (n0 + 128 + rowq) * K + kofs;
  const u16* pB3 = Bt + (n0 + 192 + rowq) * K + kofs;

#define STG_A(t, buf)                                               \
  {                                                                 \
    async16(pA0 + (size_t)(t)*64, (char*)lsA[buf] + tid * 16);      \
    async16(pA1 + (size_t)(t)*64, (char*)lsA[buf] + 8192 + tid * 16); \
  }
#define STG_B(t, buf)                                                  \
  {                                                                    \
    async16(pB0 + (size_t)(t)*64, (char*)lsB[buf] + tid * 16);         \
    async16(pB1 + (size_t)(t)*64, (char*)lsB[buf] + 8192 + tid * 16);  \
    async16(pB2 + (size_t)(t)*64, (char*)lsB[buf] + 16384 + tid * 16); \
    async16(pB3 + (size_t)(t)*64, (char*)lsB[buf] + 24576 + tid * 16); \
  }

  const int sw0 = ((g) ^ (lr & 7)) << 4;      // kk = 0
  const int sw1 = ((4 + g) ^ (lr & 7)) << 4;  // kk = 1

#define LDA(tb)                                                              \
  {                                                                          \
    _Pragma("unroll") for (int i2 = 0; i2 < 4; ++i2) {                       \
      const char* _p = (const char*)lsA[tb] + (wm * 64 + i2 * 16 + lr) * 128; \
      aF[i2][0] = *(const bf16x8*)(_p + sw0);                                \
      aF[i2][1] = *(const bf16x8*)(_p + sw1);                                \
    }                                                                        \
  }
#define LDB(tb, dst, nh)                                                                \
  {                                                                                     \
    _Pragma("unroll") for (int j2 = 0; j2 < 2; ++j2) {                                  \
      const char* _p = (const char*)lsB[tb] + (wn * 64 + (nh)*32 + j2 * 16 + lr) * 128; \
      dst[j2][0] = *(const bf16x8*)(_p + sw0);                                          \
      dst[j2][1] = *(const bf16x8*)(_p + sw1);                                          \
    }                                                                                   \
  }
#define MM(nh, BB)                                                                           \
  {                                                                                          \
    _Pragma("unroll") for (int i2 = 0; i2 < 4; ++i2) _Pragma("unroll") for (int j2 = 0;     \
                                                                            j2 < 2; ++j2) { \
      acc[i2][(nh)*2 + j2] = __builtin_amdgcn_mfma_f32_16x16x32_bf16(                        \
          aF[i2][0], BB[j2][0], acc[i2][(nh)*2 + j2], 0, 0, 0);                              \
      acc[i2][(nh)*2 + j2] = __builtin_amdgcn_mfma_f32_16x16x32_bf16(                        \
          aF[i2][1], BB[j2][1], acc[i2][(nh)*2 + j2], 0, 0, 0);                              \
    }                                                                                        \
  }

  f32x4 acc[4][4] = {};
  const int nk = K >> 6;  // K-tiles of 64; K=2048 -> 32

  // prologue: stage tiles 0,1 into bufs 0,1 (12 loads); vmcnt(6) -> tile 0 resident
  STG_A(0, 0);
  STG_B(0, 0);
  STG_A(1, 1);
  STG_B(1, 1);
  VM6;
  BAR;

  bf16x8 aF[4][2], b01[2][2], b23[2][2];
#pragma unroll 1
  for (int kt = 0; kt < nk; ++kt) {
    const int tb = kt % 3;
    const int sb = (kt + 2) % 3;
    const bool stg = (kt + 2) < nk;
    // ph1: read A-frags + B cols 0..63 of wave; stage A(kt+2); MFMA n-half 0
    LDA(tb);
    LDB(tb, b01, 0);
    if (stg) STG_A(kt + 2, sb);
    BAR;
    LGKM0;
    P1;
    MM(0, b01);
    P0;
    BAR;
    // ph2: read B cols 64..127 of wave; stage B(kt+2); MFMA n-half 1
    LDB(tb, b23, 1);
    if (stg) STG_B(kt + 2, sb);
    BAR;
    LGKM0;
    P1;
    MM(1, b23);
    P0;
    if (kt < nk - 2) {
      VM6;
    } else {
      VM0;
    }
    BAR;
  }
#undef STG_A
#undef STG_B
#undef LDA
#undef LDB
#undef MM

  if (EPI == 0) {
#pragma unroll
    for (int i = 0; i < 4; ++i)
#pragma unroll
      for (int j = 0; j < 4; ++j)
#pragma unroll
        for (int r = 0; r < 4; ++r) {
          size_t m = m0 + wm * 64 + i * 16 + 4 * g + r;
          size_t n = n0 + wn * 64 + j * 16 + lr;
          C[m * N + n] = acc[i][j][r];
        }
  } else {
    // chunk c (128 cols, wave-uniform) -> (h, part); sigma-permuted columns:
    // frag (wn1, j, lr) holds original d = wn1*32 + (j>>1)*16 + (j&1)*64 + lr
    const int c = (int)(n0 >> 7) + (wn >> 1);
    const int h = c / 3, part = c % 3;
    const int wn1 = wn & 1;
    if (part == 2) {
      // V: un-permute, write transposed (B,H,HD,S); 4 r = 4 consecutive s
#pragma unroll
      for (int i = 0; i < 4; ++i) {
        int m = (int)m0 + wm * 64 + i * 16 + 4 * g;
        int b = m >> 11, s = m & (S_ - 1);
#pragma unroll
        for (int j = 0; j < 4; ++j) {
          int hd = wn1 * 32 + ((j >> 1) << 4) + ((j & 1) << 6) + lr;
          ushort4 pk;
          pk.x = f2bf(acc[i][j][0]);
          pk.y = f2bf(acc[i][j][1]);
          pk.z = f2bf(acc[i][j][2]);
          pk.w = f2bf(acc[i][j][3]);
          *(ushort4*)(Vo + ((size_t)(b * H_ + h) * HD_ + hd) * S_ + s) = pk;
        }
      }
    } else {
      // Q/K: in-register RoPE; pairs (j=2t, j=2t+1) = (d, d+64), d = wn1*32 + t*16 + lr.
      // Stored fragment-native: jidx = wn1*64 + lr*4 + t*2 + half (one ushort4/row)
      u16* dstp = (part == 0) ? Qo : Ko;
      const float scl = (part == 0) ? 0.08838834764831845f : 1.0f;
#pragma unroll
      for (int i = 0; i < 4; ++i) {
        int mbase = (int)m0 + wm * 64 + i * 16 + 4 * g;
#pragma unroll
        for (int r = 0; r < 4; ++r) {
          int m = mbase + r;
          int b = m >> 11, s = m & (S_ - 1);
          const float* srow = rsin + s * 64;
          const float* crow = rcos + s * 64;
          u16* op = dstp + ((size_t)(b * H_ + h) * S_ + s) * HD_ + ((wn1 * 16 + lr) << 2);
          ushort4 pk;
          {
            int d = wn1 * 32 + lr;
            float cv = crow[d] * scl, sv = srow[d] * scl;
            float x1 = acc[i][0][r], x2 = acc[i][1][r];
            pk.x = f2bf(x1 * cv - x2 * sv);
            pk.y = f2bf(x2 * cv + x1 * sv);
          }
          {
            int d = wn1 * 32 + 16 + lr;
            float cv = crow[d] * scl, sv = srow[d] * scl;
            float x1 = acc[i][2][r], x2 = acc[i][3][r];
            pk.z = f2bf(x1 * cv - x2 * sv);
            pk.w = f2bf(x2 * cv + x1 * sv);
          }
          *(ushort4*)op = pk;
        }
      }
    }
  }
}

// ---------------- flash attention (R6 known-good version) ----------------
// Q,K (B,H,S,HD) sigma-j-layout roped (Q pre-scaled), VT (B,H,HD,S).
// X out (B,S,H,HD) attn-native j2-layout. grid (NT/2, 32), block 256 (4 waves).
__global__ __launch_bounds__(256) void attn_fwd(const u16* __restrict__ Q, const u16* __restrict__ K,
                                                const u16* __restrict__ VT, u16* __restrict__ X) {
  const int bx = blockIdx.x;
  const int bh = blockIdx.y;
  const int tid = threadIdx.x;
  const int lane = tid & 63, wid = tid >> 6;
  const int g = lane >> 4, lr = lane & 15;

  __shared__ alignas(16) u16 lsK[2][64 * 128];
  __shared__ alignas(16) u16 lsV[2][128 * 64];
  __shared__ alignas(16) u16 lsP[4][16 * 72];

  const u16* Qp = Q + (size_t)bh * S_ * HD_;
  const u16* Kp = K + (size_t)bh * S_ * HD_;
  const u16* Vp = VT + (size_t)bh * HD_ * S_;
  u16* myP = lsP[wid];
  const int b = bh >> 4, h = bh & 15;

  const float c1 = -0.057707802f;   // -0.04 * log2(e)
  const float c2 = -144.26950409f;  // -100 * log2(e)

#pragma unroll 1
  for (int pass = 0; pass < 2; ++pass) {
    const int qt = pass ? bx : (NT_ - 1 - bx);
    const int qrow = qt * 64 + wid * 16 + lr;
    const int qbase = qt * 64 + wid * 16 + 4 * g;

    bf16x8 qf[4];
#pragma unroll
    for (int kc = 0; kc < 4; ++kc)
      qf[kc] = *(const bf16x8*)(Qp + (size_t)qrow * HD_ + kc * 32 + g * 8);

    f32x4 o[8] = {};
    float psum[4] = {0.f, 0.f, 0.f, 0.f};

#pragma unroll
    for (int p = 0; p < 4; ++p) {
      int c = p * 256 + tid;
      int rowk = c >> 4;
      int wsk = ((c & 15) << 4) ^ ((rowk & 7) << 4);
      async16((const char*)Kp + (((size_t)rowk) << 8) + wsk, (char*)lsK[0] + c * 16);
      int rowv = c >> 3;
      int wsv = ((c & 7) << 4) ^ ((rowv & 7) << 4);
      async16((const char*)Vp + (size_t)rowv * (S_ * 2) + wsv, (char*)lsV[0] + c * 16);
    }
    __syncthreads();

    int cur = 0;
    for (int kt = 0; kt <= qt; ++kt) {
      if (kt < qt) {
        const int nxt = kt + 1;
#pragma unroll
        for (int p = 0; p < 4; ++p) {
          int c = p * 256 + tid;
          int rowk = c >> 4;
          int wsk = ((c & 15) << 4) ^ ((rowk & 7) << 4);
          async16((const char*)Kp + (((size_t)(nxt * 64 + rowk)) << 8) + wsk,
                  (char*)lsK[cur ^ 1] + c * 16);
          int rowv = c >> 3;
          int wsv = ((c & 7) << 4) ^ ((rowv & 7) << 4);
          async16((const char*)Vp + (size_t)rowv * (S_ * 2) + nxt * 128 + wsv,
                  (char*)lsV[cur ^ 1] + c * 16);
        }
      }
      f32x4 sc[4];
#pragma unroll
      for (int jn = 0; jn < 4; ++jn) {
        f32x4 a = {0.f, 0.f, 0.f, 0.f};
        const int row = jn * 16 + lr;
        const int sw = (row & 7) << 4;
#pragma unroll
        for (int kc = 0; kc < 4; ++kc) {
          int w = (kc * 64 + g * 16) ^ sw;
          bf16x8 kf = *(const bf16x8*)((const char*)lsK[cur] + row * 256 + w);
          a = __builtin_amdgcn_mfma_f32_16x16x32_bf16(qf[kc], kf, a, 0, 0, 0);
        }
        sc[jn] = a;
      }
#pragma unroll
      for (int jn = 0; jn < 4; ++jn) {
        int key = kt * 64 + jn * 16 + lr;
#pragma unroll
        for (int r = 0; r < 4; ++r) {
          float z = vexp2(c1 * sc[jn][r]);
          float p = vexp2(c2 * z * vrcp(1.f + z));
          if (key > qbase + r) p = 0.f;
          psum[r] += p;
          myP[(4 * g + r) * 72 + jn * 16 + lr] = f2bf(p);
        }
      }
#pragma unroll
      for (int kc = 0; kc < 2; ++kc) {
        bf16x8 pa = *(const bf16x8*)(myP + lr * 72 + kc * 32 + g * 8);
#pragma unroll
        for (int jh = 0; jh < 8; ++jh) {
          int row = jh * 16 + lr;
          int w = (kc * 64 + g * 16) ^ ((row & 7) << 4);
          bf16x8 vf = *(const bf16x8*)((const char*)lsV[cur] + row * 128 + w);
          o[jh] = __builtin_amdgcn_mfma_f32_16x16x32_bf16(pa, vf, o[jh], 0, 0, 0);
        }
      }
      __syncthreads();
      cur ^= 1;
    }
    float lsum[4];
#pragma unroll
    for (int r = 0; r < 4; ++r) {
      float s = psum[r];
#pragma unroll
      for (int msk = 1; msk < 16; msk <<= 1) s += __shfl_xor(s, msk, 64);
      lsum[r] = s;
    }
#pragma unroll
    for (int r = 0; r < 4; ++r) {
      float inv = 1.f / lsum[r];
      int s = qbase + r;
      u16x8 pk;
#pragma unroll
      for (int jh = 0; jh < 8; ++jh) pk[jh] = f2bf(o[jh][r] * inv);
      *(u16x8*)(X + ((size_t)(b * S_ + s)) * D_ + h * HD_ + lr * 8) = pk;
    }
  }
}

extern "C" void kernel_launch(void* const* d_in, const int* in_sizes, int n_in,
                              void* d_out, int out_size, void* d_ws, size_t ws_size,
                              hipStream_t stream) {
  const float* inputs = (const float*)d_in[0];
  const float* w_in = (const float*)d_in[1];
  const float* w_out = (const float*)d_in[2];
  const float* rsin = (const float*)d_in[3];
  const float* rcos = (const float*)d_in[4];
  float* out = (float*)d_out;

  char* ws = (char*)d_ws;
  u16* bfA = (u16*)(ws);                // (B*S, D) bf16
  u16* w_inT = (u16*)(ws + 16777216);   // (6144, 2048) bf16, sigma-permuted cols
  u16* Qraw = (u16*)(ws + 41943040);    // (B,H,S,HD) roped, j-layout, Q pre-scaled
  u16* Kraw = (u16*)(ws + 58720256);    // (B,H,S,HD) roped, j-layout
  u16* VT = (u16*)(ws + 75497472);      // (B,H,HD,S)
  u16* Xbuf = (u16*)(ws);               // reuse bfA region, j2-layout
  u16* w_outT = (u16*)(ws + 16777216);  // reuse w_inT region, row-permuted

  conv_f32_bf16<<<2048, 256, 0, stream>>>(inputs, bfA, B_ * S_ * D_);
  transpose_win<<<dim3(192, 64), 256, 0, stream>>>(w_in, w_inT);
  gemm128<1><<<768, 512, 0, stream>>>(bfA, w_inT, nullptr, 2048, 6144, 24, Qraw, Kraw, VT,
                                      rsin, rcos);
  transpose_wout<<<dim3(64, 64), 256, 0, stream>>>(w_out, w_outT);
  attn_fwd<<<dim3(NT_ / 2, 32), 256, 0, stream>>>(Qraw, Kraw, VT, Xbuf);
  gemm128<0><<<256, 512, 0, stream>>>(Xbuf, w_outT, out, 2048, 2048, 8,
                                      nullptr, nullptr, nullptr, nullptr, nullptr);
}

// Round 9
// 278.204 us; speedup vs baseline: 1.0417x; 1.0004x over previous
//
#include <hip/hip_runtime.h>

#define B_ 2
#define S_ 2048
#define D_ 2048
#define H_ 16
#define HD_ 128
#define NT_ (S_ / 64)

typedef unsigned short u16;
typedef __bf16 bf16x8 __attribute__((ext_vector_type(8)));
typedef float f32x4 __attribute__((ext_vector_type(4)));
typedef float f32x16 __attribute__((ext_vector_type(16)));
typedef u16 u16x8 __attribute__((ext_vector_type(8)));

__device__ __forceinline__ float bf2f(u16 u) {
  unsigned int x = ((unsigned int)u) << 16;
  return __builtin_bit_cast(float, x);
}
__device__ __forceinline__ u16 f2bf(float f) {
  unsigned int u = __builtin_bit_cast(unsigned int, f);
  u += 0x7fffu + ((u >> 16) & 1u);
  return (u16)(u >> 16);
}
__device__ __forceinline__ void async16(const void* g, void* l) {
  __builtin_amdgcn_global_load_lds((const __attribute__((address_space(1))) void*)g,
                                   (__attribute__((address_space(3))) void*)l, 16, 0, 0);
}
__device__ __forceinline__ float vexp2(float x) {
  float r;
  asm("v_exp_f32 %0, %1" : "=v"(r) : "v"(x));
  return r;
}
__device__ __forceinline__ float vrcp(float x) {
  float r;
  asm("v_rcp_f32 %0, %1" : "=v"(r) : "v"(x));
  return r;
}

// ---------------- elementwise fp32 -> bf16 ----------------
__global__ __launch_bounds__(256) void conv_f32_bf16(const float* __restrict__ in,
                                                     u16* __restrict__ outp, int n) {
  int idx = (blockIdx.x * 256 + threadIdx.x) * 4;
  int stride = gridDim.x * 256 * 4;
  for (; idx < n; idx += stride) {
    float4 v = *(const float4*)(in + idx);
    ushort4 ov = make_ushort4(f2bf(v.x), f2bf(v.y), f2bf(v.z), f2bf(v.w));
    *(ushort4*)(outp + idx) = ov;
  }
}

// ---------------- w_in transpose+convert with sigma column permutation ----------------
// out row n (chunk cc = n>>7, p = n&127) holds w_in column f = (cc/3)*384 + (cc%3)*128 + d,
// d = (p>>6)*32 + ((p>>5)&1)*64 + (p&31)   [32x32-MFMA fragment-native sigma]
__global__ __launch_bounds__(256) void transpose_win(const float* __restrict__ in,
                                                     u16* __restrict__ outp) {
  __shared__ float tile[32][33];
  int n0 = blockIdx.x * 32, k0 = blockIdx.y * 32;
  int tx = threadIdx.x & 31, ty = threadIdx.x >> 5;
  int n = n0 + tx;
  int cc = n >> 7, p = n & 127;
  int d = ((p >> 6) << 5) + (((p >> 5) & 1) << 6) + (p & 31);
  int f = (cc / 3) * 384 + (cc % 3) * 128 + d;
#pragma unroll
  for (int yy = 0; yy < 32; yy += 8)
    tile[ty + yy][tx] = in[(size_t)(k0 + ty + yy) * 6144 + f];
  __syncthreads();
#pragma unroll
  for (int yy = 0; yy < 32; yy += 8)
    outp[(size_t)(n0 + ty + yy) * 2048 + k0 + tx] = f2bf(tile[tx][ty + yy]);
}

// ---------------- w_out transpose+convert with row permutation matching X' layout ----------
__global__ __launch_bounds__(256) void transpose_wout(const float* __restrict__ in,
                                                      u16* __restrict__ outp) {
  __shared__ float tile[32][33];
  int k0 = blockIdx.x * 32, n0 = blockIdx.y * 32;
  int tx = threadIdx.x & 31, ty = threadIdx.x >> 5;
#pragma unroll
  for (int yy = 0; yy < 32; yy += 8) {
    int kk = k0 + ty + yy;
    int hh = kk >> 7, j = kk & 127;
    int hd = (j & 7) * 16 + (j >> 3);
    tile[ty + yy][tx] = in[(size_t)(hh * 128 + hd) * 2048 + n0 + tx];
  }
  __syncthreads();
#pragma unroll
  for (int yy = 0; yy < 32; yy += 8)
    outp[(size_t)(n0 + ty + yy) * 2048 + k0 + tx] = f2bf(tile[tx][ty + yy]);
}

// ================= 128x256 GEMM, BK=64, 3-ring, 32x32x16 MFMA, ONE barrier/K-tile ========
// 8 waves (2M x 4N), per-wave 64x64 = 2x2 frags of 32x32. 16 MFMA per K64-tile per wave.
// Ring safety: end-barrier of iter kt means all waves' reads of buf kt%3 drained
// (per-wave lgkmcnt(0) precedes it); a wave in kt+1 staging (kt+3)%3 therefore cannot race.
// Arrival: vmcnt(6) at each iter end -> tile kt+2's loads (issued in kt) drained.
#define BAR __builtin_amdgcn_s_barrier()
#define LGKM0                                          \
  {                                                    \
    asm volatile("s_waitcnt lgkmcnt(0)" ::: "memory"); \
    __builtin_amdgcn_sched_barrier(0);                 \
  }
#define VM6 asm volatile("s_waitcnt vmcnt(6)" ::: "memory")
#define VM0 asm volatile("s_waitcnt vmcnt(0)" ::: "memory")
#define P1 __builtin_amdgcn_s_setprio(1)
#define P0 __builtin_amdgcn_s_setprio(0)

template <int EPI>
__global__ __launch_bounds__(512, 1) void gemm128(
    const u16* __restrict__ A, const u16* __restrict__ Bt, float* __restrict__ C, int K, int N,
    int ntn, u16* __restrict__ Qo, u16* __restrict__ Ko, u16* __restrict__ Vo,
    const float* __restrict__ rsin, const float* __restrict__ rcos) {
  __shared__ alignas(16) u16 lsA[3][128 * 64];
  __shared__ alignas(16) u16 lsB[3][256 * 64];
  const int tid = threadIdx.x;
  const int lane = tid & 63, wid = tid >> 6;
  const int c31 = lane & 31, hh = lane >> 5;
  const int wm = wid >> 2, wn = wid & 3;  // 2M x 4N, wave tile 64x64

  // bijective XCD swizzle (nwg % 8 == 0 at both call sites)
  const int nwg = ntn << 5;  // 32 m-tiles always
  const int bid = blockIdx.x;
  const int swz = (bid & 7) * (nwg >> 3) + (bid >> 3);
  const int m_idx = swz & 31, n_idx = swz >> 5;
  const size_t m0 = (size_t)m_idx * 128, n0 = (size_t)n_idx * 256;

  // staging sources: chunk idx -> row = idx>>3, slot = idx&7; global k pre-swizzled
  const int rowq = tid >> 3, slq = tid & 7;
  const int kofs = (slq ^ (rowq & 7)) << 3;
  const u16* pA0 = A + (m0 + rowq) * K + kofs;
  const u16* pA1 = A + (m0 + 64 + rowq) * K + kofs;
  const u16* pB0 = Bt + (n0 + rowq) * K + kofs;
  const u16* pB1 = Bt + (n0 + 64 + rowq) * K + kofs;
  const u16* pB2 = Bt + (n0 + 128 + rowq) * K + kofs;
  const u16* pB3 = Bt + (n0 + 192 + rowq) * K + kofs;

#define STG_A(t, buf)                                                 \
  {                                                                   \
    async16(pA0 + (size_t)(t)*64, (char*)lsA[buf] + tid * 16);        \
    async16(pA1 + (size_t)(t)*64, (char*)lsA[buf] + 8192 + tid * 16); \
  }
#define STG_B(t, buf)                                                  \
  {                                                                    \
    async16(pB0 + (size_t)(t)*64, (char*)lsB[buf] + tid * 16);         \
    async16(pB1 + (size_t)(t)*64, (char*)lsB[buf] + 8192 + tid * 16);  \
    async16(pB2 + (size_t)(t)*64, (char*)lsB[buf] + 16384 + tid * 16); \
    async16(pB3 + (size_t)(t)*64, (char*)lsB[buf] + 24576 + tid * 16); \
  }

  // ds_read byte offsets: A row = wm*64 + mi*32 + c31; k-slot = (t*2 + hh) ^ (row & 7)
  // (row & 7 == c31 & 7). Same swizzle family as R8 (conflict-counter-verified 0).
  int ofsA[2][4], ofsB[2][4];
#pragma unroll
  for (int mi = 0; mi < 2; ++mi)
#pragma unroll
    for (int t = 0; t < 4; ++t) {
      int ra = wm * 64 + mi * 32 + c31;
      ofsA[mi][t] = ra * 128 + (((t * 2 + hh) ^ (c31 & 7)) << 4);
      int rb = wn * 64 + mi * 32 + c31;
      ofsB[mi][t] = rb * 128 + (((t * 2 + hh) ^ (c31 & 7)) << 4);
    }

  f32x16 acc[2][2] = {};
  const int nk = K >> 6;  // K64-tiles; K=2048 -> 32

  // prologue: stage tiles 0,1 into bufs 0,1 (12 loads); vmcnt(6) -> tile 0 resident
  STG_A(0, 0);
  STG_B(0, 0);
  STG_A(1, 1);
  STG_B(1, 1);
  VM6;
  BAR;

#pragma unroll 1
  for (int kt = 0; kt < nk; ++kt) {
    const int tb = kt % 3;
    const int sb = (kt + 2) % 3;
    const bool stg = (kt + 2) < nk;
    bf16x8 aF[2][4], bF[2][4];
#pragma unroll
    for (int mi = 0; mi < 2; ++mi)
#pragma unroll
      for (int t = 0; t < 4; ++t)
        aF[mi][t] = *(const bf16x8*)((const char*)lsA[tb] + ofsA[mi][t]);
#pragma unroll
    for (int ni = 0; ni < 2; ++ni)
#pragma unroll
      for (int t = 0; t < 4; ++t)
        bF[ni][t] = *(const bf16x8*)((const char*)lsB[tb] + ofsB[ni][t]);
    if (stg) {
      STG_A(kt + 2, sb);
      STG_B(kt + 2, sb);
    }
    LGKM0;
    P1;
#pragma unroll
    for (int t = 0; t < 4; ++t)
#pragma unroll
      for (int mi = 0; mi < 2; ++mi)
#pragma unroll
        for (int ni = 0; ni < 2; ++ni)
          acc[mi][ni] =
              __builtin_amdgcn_mfma_f32_32x32x16_bf16(aF[mi][t], bF[ni][t], acc[mi][ni], 0, 0, 0);
    P0;
    if (kt < nk - 2) {
      VM6;
    } else {
      VM0;
    }
    BAR;
  }
#undef STG_A
#undef STG_B

  // C/D layout (HW-verified m74/m101): col = c31 (B/n-dim), row = (reg&3) + 8*(reg>>2) + 4*hh
  if (EPI == 0) {
#pragma unroll
    for (int mi = 0; mi < 2; ++mi)
#pragma unroll
      for (int ni = 0; ni < 2; ++ni)
#pragma unroll
        for (int reg = 0; reg < 16; ++reg) {
          size_t m = m0 + wm * 64 + mi * 32 + (reg & 3) + 8 * (reg >> 2) + 4 * hh;
          size_t n = n0 + wn * 64 + ni * 32 + c31;
          C[m * N + n] = acc[mi][ni][reg];
        }
  } else {
    // chunk c (128 cols) -> (h, part); sigma: position p = wn1*64 + ni*32 + c31 holds
    // original d = wn1*32 + c31 + 64*ni  ->  (ni=0, ni=1) are the RoPE pair (d, d+64).
    const int c = (int)(n0 >> 7) + (wn >> 1);
    const int h = c / 3, part = c % 3;
    const int wn1 = wn & 1;
    if (part == 2) {
      // V: un-permute, write transposed (B,H,HD,S); reg&3 = 4 consecutive s -> ushort4
#pragma unroll
      for (int mi = 0; mi < 2; ++mi)
#pragma unroll
        for (int ni = 0; ni < 2; ++ni) {
          int hd = wn1 * 32 + c31 + 64 * ni;
#pragma unroll
          for (int rq = 0; rq < 4; ++rq) {
            int m = (int)m0 + wm * 64 + mi * 32 + 8 * rq + 4 * hh;
            int b = m >> 11, s = m & (S_ - 1);
            ushort4 pk;
            pk.x = f2bf(acc[mi][ni][rq * 4 + 0]);
            pk.y = f2bf(acc[mi][ni][rq * 4 + 1]);
            pk.z = f2bf(acc[mi][ni][rq * 4 + 2]);
            pk.w = f2bf(acc[mi][ni][rq * 4 + 3]);
            *(ushort4*)(Vo + ((size_t)(b * H_ + h) * HD_ + hd) * S_ + s) = pk;
          }
        }
    } else {
      // Q/K: in-register RoPE (pair across ni), store fragment-native:
      // jidx = c31*4 + wn1*2 + {0,1}  (bijective over 128; Q and K share it)
      u16* dstp = (part == 0) ? Qo : Ko;
      const float scl = (part == 0) ? 0.08838834764831845f : 1.0f;
      const int d = wn1 * 32 + c31;
      const int jofs = c31 * 4 + wn1 * 2;
#pragma unroll
      for (int mi = 0; mi < 2; ++mi)
#pragma unroll
        for (int reg = 0; reg < 16; ++reg) {
          int m = (int)m0 + wm * 64 + mi * 32 + (reg & 3) + 8 * (reg >> 2) + 4 * hh;
          int b = m >> 11, s = m & (S_ - 1);
          float cv = rcos[s * 64 + d] * scl, sv = rsin[s * 64 + d] * scl;
          float x1 = acc[mi][0][reg], x2 = acc[mi][1][reg];
          ushort2 pk;
          pk.x = f2bf(x1 * cv - x2 * sv);
          pk.y = f2bf(x2 * cv + x1 * sv);
          *(ushort2*)(dstp + ((size_t)(b * H_ + h) * S_ + s) * HD_ + jofs) = pk;
        }
    }
  }
}

// ---------------- flash attention (R6/R8 known-good version, layout-opaque) ----------------
__global__ __launch_bounds__(256) void attn_fwd(const u16* __restrict__ Q, const u16* __restrict__ K,
                                                const u16* __restrict__ VT, u16* __restrict__ X) {
  const int bx = blockIdx.x;
  const int bh = blockIdx.y;
  const int tid = threadIdx.x;
  const int lane = tid & 63, wid = tid >> 6;
  const int g = lane >> 4, lr = lane & 15;

  __shared__ alignas(16) u16 lsK[2][64 * 128];
  __shared__ alignas(16) u16 lsV[2][128 * 64];
  __shared__ alignas(16) u16 lsP[4][16 * 72];

  const u16* Qp = Q + (size_t)bh * S_ * HD_;
  const u16* Kp = K + (size_t)bh * S_ * HD_;
  const u16* Vp = VT + (size_t)bh * HD_ * S_;
  u16* myP = lsP[wid];
  const int b = bh >> 4, h = bh & 15;

  const float c1 = -0.057707802f;   // -0.04 * log2(e)
  const float c2 = -144.26950409f;  // -100 * log2(e)

#pragma unroll 1
  for (int pass = 0; pass < 2; ++pass) {
    const int qt = pass ? bx : (NT_ - 1 - bx);
    const int qrow = qt * 64 + wid * 16 + lr;
    const int qbase = qt * 64 + wid * 16 + 4 * g;

    bf16x8 qf[4];
#pragma unroll
    for (int kc = 0; kc < 4; ++kc)
      qf[kc] = *(const bf16x8*)(Qp + (size_t)qrow * HD_ + kc * 32 + g * 8);

    f32x4 o[8] = {};
    float psum[4] = {0.f, 0.f, 0.f, 0.f};

#pragma unroll
    for (int p = 0; p < 4; ++p) {
      int c = p * 256 + tid;
      int rowk = c >> 4;
      int wsk = ((c & 15) << 4) ^ ((rowk & 7) << 4);
      async16((const char*)Kp + (((size_t)rowk) << 8) + wsk, (char*)lsK[0] + c * 16);
      int rowv = c >> 3;
      int wsv = ((c & 7) << 4) ^ ((rowv & 7) << 4);
      async16((const char*)Vp + (size_t)rowv * (S_ * 2) + wsv, (char*)lsV[0] + c * 16);
    }
    __syncthreads();

    int cur = 0;
    for (int kt = 0; kt <= qt; ++kt) {
      if (kt < qt) {
        const int nxt = kt + 1;
#pragma unroll
        for (int p = 0; p < 4; ++p) {
          int c = p * 256 + tid;
          int rowk = c >> 4;
          int wsk = ((c & 15) << 4) ^ ((rowk & 7) << 4);
          async16((const char*)Kp + (((size_t)(nxt * 64 + rowk)) << 8) + wsk,
                  (char*)lsK[cur ^ 1] + c * 16);
          int rowv = c >> 3;
          int wsv = ((c & 7) << 4) ^ ((rowv & 7) << 4);
          async16((const char*)Vp + (size_t)rowv * (S_ * 2) + nxt * 128 + wsv,
                  (char*)lsV[cur ^ 1] + c * 16);
        }
      }
      f32x4 sc[4];
#pragma unroll
      for (int jn = 0; jn < 4; ++jn) {
        f32x4 a = {0.f, 0.f, 0.f, 0.f};
        const int row = jn * 16 + lr;
        const int sw = (row & 7) << 4;
#pragma unroll
        for (int kc = 0; kc < 4; ++kc) {
          int w = (kc * 64 + g * 16) ^ sw;
          bf16x8 kf = *(const bf16x8*)((const char*)lsK[cur] + row * 256 + w);
          a = __builtin_amdgcn_mfma_f32_16x16x32_bf16(qf[kc], kf, a, 0, 0, 0);
        }
        sc[jn] = a;
      }
#pragma unroll
      for (int jn = 0; jn < 4; ++jn) {
        int key = kt * 64 + jn * 16 + lr;
#pragma unroll
        for (int r = 0; r < 4; ++r) {
          float z = vexp2(c1 * sc[jn][r]);
          float p = vexp2(c2 * z * vrcp(1.f + z));
          if (key > qbase + r) p = 0.f;
          psum[r] += p;
          myP[(4 * g + r) * 72 + jn * 16 + lr] = f2bf(p);
        }
      }
#pragma unroll
      for (int kc = 0; kc < 2; ++kc) {
        bf16x8 pa = *(const bf16x8*)(myP + lr * 72 + kc * 32 + g * 8);
#pragma unroll
        for (int jh = 0; jh < 8; ++jh) {
          int row = jh * 16 + lr;
          int w = (kc * 64 + g * 16) ^ ((row & 7) << 4);
          bf16x8 vf = *(const bf16x8*)((const char*)lsV[cur] + row * 128 + w);
          o[jh] = __builtin_amdgcn_mfma_f32_16x16x32_bf16(pa, vf, o[jh], 0, 0, 0);
        }
      }
      __syncthreads();
      cur ^= 1;
    }
    float lsum[4];
#pragma unroll
    for (int r = 0; r < 4; ++r) {
      float s = psum[r];
#pragma unroll
      for (int msk = 1; msk < 16; msk <<= 1) s += __shfl_xor(s, msk, 64);
      lsum[r] = s;
    }
#pragma unroll
    for (int r = 0; r < 4; ++r) {
      float inv = 1.f / lsum[r];
      int s = qbase + r;
      u16x8 pk;
#pragma unroll
      for (int jh = 0; jh < 8; ++jh) pk[jh] = f2bf(o[jh][r] * inv);
      *(u16x8*)(X + ((size_t)(b * S_ + s)) * D_ + h * HD_ + lr * 8) = pk;
    }
  }
}

extern "C" void kernel_launch(void* const* d_in, const int* in_sizes, int n_in,
                              void* d_out, int out_size, void* d_ws, size_t ws_size,
                              hipStream_t stream) {
  const float* inputs = (const float*)d_in[0];
  const float* w_in = (const float*)d_in[1];
  const float* w_out = (const float*)d_in[2];
  const float* rsin = (const float*)d_in[3];
  const float* rcos = (const float*)d_in[4];
  float* out = (float*)d_out;

  char* ws = (char*)d_ws;
  u16* bfA = (u16*)(ws);                // (B*S, D) bf16
  u16* w_inT = (u16*)(ws + 16777216);   // (6144, 2048) bf16, sigma-permuted cols
  u16* Qraw = (u16*)(ws + 41943040);    // (B,H,S,HD) roped, j-layout, Q pre-scaled
  u16* Kraw = (u16*)(ws + 58720256);    // (B,H,S,HD) roped, j-layout
  u16* VT = (u16*)(ws + 75497472);      // (B,H,HD,S)
  u16* Xbuf = (u16*)(ws);               // reuse bfA region, j2-layout
  u16* w_outT = (u16*)(ws + 16777216);  // reuse w_inT region, row-permuted

  conv_f32_bf16<<<2048, 256, 0, stream>>>(inputs, bfA, B_ * S_ * D_);
  transpose_win<<<dim3(192, 64), 256, 0, stream>>>(w_in, w_inT);
  gemm128<1><<<768, 512, 0, stream>>>(bfA, w_inT, nullptr, 2048, 6144, 24, Qraw, Kraw, VT,
                                      rsin, rcos);
  transpose_wout<<<dim3(64, 64), 256, 0, stream>>>(w_out, w_outT);
  attn_fwd<<<dim3(NT_ / 2, 32), 256, 0, stream>>>(Qraw, Kraw, VT, Xbuf);
  gemm128<0><<<256, 512, 0, stream>>>(Xbuf, w_outT, out, 2048, 2048, 8,
                                      nullptr, nullptr, nullptr, nullptr, nullptr);
}